// Round 2
// baseline (2461.794 us; speedup 1.0000x reference)
//
#include <hip/hip_runtime.h>
#include <hip/hip_bf16.h>

// NGCF forward on MI355X.
// CSR build from unsorted COO (hist+scan+scatter), then 3x { atomic-free SpMM
// (wave per row, lane = dim), dense GCN+bi branch (wave per node, W in LDS,
// shfl broadcast), normalize+gather only the 8192 output rows to d_out }.
// Float dtype (f32 vs bf16) is detected at runtime from user_emb's bit
// pattern; all conversion points branch uniformly on the flag.

#define N_USER 100000
#define N_ITEM 50000
#define N_NODES 150000
#define NE 4800000
#define D 64
#define NB1 ((N_NODES + 255) / 256)  // 586 blocks for the scan

typedef __hip_bfloat16 bf16;

__device__ __forceinline__ float bits2f(unsigned short u) {
  unsigned int w = ((unsigned int)u) << 16;
  return __uint_as_float(w);
}

// load element i of a float array that is either f32 (flag=1) or bf16 (flag=0)
__device__ __forceinline__ float loadF(const void* p, long i, int f32) {
  if (f32) return ((const float*)p)[i];
  return bits2f(((const unsigned short*)p)[i]);
}

__global__ void k_zero(int* __restrict__ p, int n) {
  int i = blockIdx.x * blockDim.x + threadIdx.x;
  if (i < n) p[i] = 0;
}

// flag <- 1 if user_emb buffer is float32, 0 if bf16.
// Reading f32 data as bf16 yields random exponents -> some |v| >= 1e4 or NaN.
__global__ void k_detect(const unsigned short* __restrict__ ue, int* __restrict__ flag) {
  int bad = 0;
  for (int t = threadIdx.x; t < 512; t += 256) {
    float f = fabsf(bits2f(ue[t]));
    if (!(f < 1e4f)) bad = 1;  // catches NaN/Inf too
  }
  if (bad) atomicOr(flag, 1);
}

// ego[N,64] fp32 <- concat(user_emb, item_emb)
__global__ void k_init_ego(const void* __restrict__ ue, const void* __restrict__ ie,
                           float* __restrict__ ego, const int* __restrict__ flag) {
  int f32 = *flag;
  int i = blockIdx.x * blockDim.x + threadIdx.x;
  if (i < N_USER * D) ego[i] = loadF(ue, i, f32);
  else if (i < N_NODES * D) ego[i] = loadF(ie, i - N_USER * D, f32);
}

__global__ void k_hist(const int* __restrict__ row, int* __restrict__ hist) {
  int e = blockIdx.x * blockDim.x + threadIdx.x;
  if (e < NE) atomicAdd(&hist[row[e]], 1);
}

// per-block exclusive scan (in-place over hist->rp), block sums to bsum
__global__ void k_scan1(int* __restrict__ rp, int* __restrict__ bsum) {
  __shared__ int sh[256];
  int i = blockIdx.x * 256 + threadIdx.x;
  int v = (i < N_NODES) ? rp[i] : 0;
  sh[threadIdx.x] = v;
  __syncthreads();
  for (int off = 1; off < 256; off <<= 1) {
    int t = (threadIdx.x >= off) ? sh[threadIdx.x - off] : 0;
    __syncthreads();
    sh[threadIdx.x] += t;
    __syncthreads();
  }
  if (i < N_NODES) rp[i] = sh[threadIdx.x] - v;  // exclusive within block
  if (threadIdx.x == 255) bsum[blockIdx.x] = sh[255];
}

// single-block exclusive scan of the 586 block sums
__global__ void k_scan2(int* __restrict__ bsum) {
  __shared__ int sh[1024];
  int tid = threadIdx.x;
  int v = (tid < NB1) ? bsum[tid] : 0;
  sh[tid] = v;
  __syncthreads();
  for (int off = 1; off < 1024; off <<= 1) {
    int t = (tid >= off) ? sh[tid - off] : 0;
    __syncthreads();
    sh[tid] += t;
    __syncthreads();
  }
  if (tid < NB1) bsum[tid] = sh[tid] - v;
}

__global__ void k_scan3(int* __restrict__ rp, const int* __restrict__ bsum,
                        int* __restrict__ cursor) {
  int i = blockIdx.x * blockDim.x + threadIdx.x;
  if (i < N_NODES) {
    int v = rp[i] + bsum[i >> 8];
    rp[i] = v;
    cursor[i] = v;
  }
  if (i == 0) rp[N_NODES] = NE;
}

__global__ void k_scatter(const int* __restrict__ row, const int* __restrict__ col,
                          const void* __restrict__ val, int* __restrict__ cursor,
                          int* __restrict__ col_s, float* __restrict__ val_s,
                          const int* __restrict__ flag) {
  int f32 = *flag;
  int e = blockIdx.x * blockDim.x + threadIdx.x;
  if (e < NE) {
    int r = row[e];
    int pos = atomicAdd(&cursor[r], 1);
    col_s[pos] = col[e];
    val_s[pos] = loadF(val, e, f32);
  }
}

// side[r,:] = sum_e val[e] * ego[col[e],:]   one wave per row, lane = dim
__global__ void k_spmm(const int* __restrict__ rp, const int* __restrict__ col_s,
                       const float* __restrict__ val_s, const float* __restrict__ ego,
                       float* __restrict__ side) {
  int r = blockIdx.x * 4 + (threadIdx.x >> 6);
  int lane = threadIdx.x & 63;
  if (r >= N_NODES) return;
  int s = rp[r], e = rp[r + 1];
  float acc = 0.f;
  int i = s;
  for (; i + 2 <= e; i += 2) {
    int c0 = col_s[i];
    int c1 = col_s[i + 1];
    float v0 = val_s[i];
    float v1 = val_s[i + 1];
    float g0 = ego[c0 * D + lane];
    float g1 = ego[c1 * D + lane];
    acc += v0 * g0;
    acc += v1 * g1;
  }
  if (i < e) acc += val_s[i] * ego[col_s[i] * D + lane];
  side[r * D + lane] = acc;
}

// ego[r,:] = leaky_relu(side@Wgc + bgc + (ego*side)@Wbi + bbi), in place.
// one wave per node; W staged fp32 in LDS; side/prod broadcast via shfl.
__global__ void k_dense(const void* __restrict__ Wgc, const void* __restrict__ bgc,
                        const void* __restrict__ Wbi, const void* __restrict__ bbi,
                        const float* __restrict__ side, float* __restrict__ ego,
                        int layer, const int* __restrict__ flag) {
  __shared__ float sWg[64 * 64];
  __shared__ float sWb[64 * 64];
  __shared__ float sbg[64];
  __shared__ float sbb[64];
  int f32 = *flag;
  int tid = threadIdx.x;
  for (int t = tid; t < 4096; t += 256) {
    sWg[t] = loadF(Wgc, (long)layer * 4096 + t, f32);
    sWb[t] = loadF(Wbi, (long)layer * 4096 + t, f32);
  }
  if (tid < 64) {
    sbg[tid] = loadF(bgc, layer * 64 + tid, f32);
    sbb[tid] = loadF(bbi, layer * 64 + tid, f32);
  }
  __syncthreads();
  int r = blockIdx.x * 4 + (tid >> 6);
  int lane = tid & 63;
  if (r >= N_NODES) return;
  float s = side[r * D + lane];
  float eg = ego[r * D + lane];
  float p = eg * s;
  float accg = sbg[lane];
  float accb = sbb[lane];
#pragma unroll 16
  for (int j = 0; j < 64; ++j) {
    float sj = __shfl(s, j);
    float pj = __shfl(p, j);
    accg += sj * sWg[j * 64 + lane];
    accb += pj * sWb[j * 64 + lane];
  }
  float x = accg + accb;
  x = (x > 0.f) ? x : 0.2f * x;
  ego[r * D + lane] = x;
}

// gather 8192 output rows into out slice; optional l2-normalize per row.
// b < 4096 -> users (u_g), else items (i_g). out layout: [8192, 256].
__global__ void k_gather(const float* __restrict__ ego, const int* __restrict__ users,
                         const int* __restrict__ items, void* __restrict__ out,
                         int slice, int do_norm, const int* __restrict__ flag) {
  int f32 = *flag;
  int b = blockIdx.x * 4 + (threadIdx.x >> 6);
  int lane = threadIdx.x & 63;
  if (b >= 8192) return;
  int r = (b < 4096) ? users[b] : (N_USER + items[b - 4096]);
  float x = ego[r * D + lane];
  float scale = 1.f;
  if (do_norm) {
    float ss = x * x;
    for (int off = 32; off > 0; off >>= 1) ss += __shfl_xor(ss, off);
    float n = sqrtf(ss);
    scale = 1.f / fmaxf(n, 1e-12f);
  }
  float y = x * scale;
  long idx = (long)b * 256 + slice * 64 + lane;
  if (f32) ((float*)out)[idx] = y;
  else ((bf16*)out)[idx] = __float2bfloat16(y);
}

extern "C" void kernel_launch(void* const* d_in, const int* in_sizes, int n_in,
                              void* d_out, int out_size, void* d_ws, size_t ws_size,
                              hipStream_t stream) {
  const void* ue = d_in[0];
  const void* ie = d_in[1];
  const void* Wgc = d_in[2];
  const void* bgc = d_in[3];
  const void* Wbi = d_in[4];
  const void* bbi = d_in[5];
  const void* aval = d_in[6];
  const int* arow = (const int*)d_in[7];
  const int* acol = (const int*)d_in[8];
  const int* users = (const int*)d_in[9];
  const int* items = (const int*)d_in[10];

  char* ws = (char*)d_ws;
  size_t off = 0;
  float* ego = (float*)(ws + off);    off += (size_t)N_NODES * D * 4;   // 38.4 MB
  float* side = (float*)(ws + off);   off += (size_t)N_NODES * D * 4;   // 38.4 MB
  int* col_s = (int*)(ws + off);      off += (size_t)NE * 4;            // 19.2 MB
  float* val_s = (float*)(ws + off);  off += (size_t)NE * 4;            // 19.2 MB
  int* rp = (int*)(ws + off);         off += (size_t)(N_NODES + 64) * 4;
  int* cursor = (int*)(ws + off);     off += (size_t)N_NODES * 4;
  int* bsum = (int*)(ws + off);       off += 4096;
  int* flag = (int*)(ws + off);       off += 256;
  (void)ws_size;

  k_zero<<<1, 64, 0, stream>>>(flag, 1);
  k_detect<<<1, 256, 0, stream>>>((const unsigned short*)ue, flag);

  // CSR build (adjacency is call-invariant but ws is re-poisoned -> rebuild)
  k_zero<<<(N_NODES + 255) / 256, 256, 0, stream>>>(rp, N_NODES);
  k_init_ego<<<(N_NODES * D + 255) / 256, 256, 0, stream>>>(ue, ie, ego, flag);
  // slice 0 = raw (un-normalized) initial ego, gathered
  k_gather<<<2048, 256, 0, stream>>>(ego, users, items, d_out, 0, 0, flag);
  k_hist<<<(NE + 255) / 256, 256, 0, stream>>>(arow, rp);
  k_scan1<<<NB1, 256, 0, stream>>>(rp, bsum);
  k_scan2<<<1, 1024, 0, stream>>>(bsum);
  k_scan3<<<NB1, 256, 0, stream>>>(rp, bsum, cursor);
  k_scatter<<<(NE + 255) / 256, 256, 0, stream>>>(arow, acol, aval, cursor, col_s, val_s, flag);

  for (int k = 0; k < 3; ++k) {
    k_spmm<<<(N_NODES + 3) / 4, 256, 0, stream>>>(rp, col_s, val_s, ego, side);
    k_dense<<<(N_NODES + 3) / 4, 256, 0, stream>>>(Wgc, bgc, Wbi, bbi, side, ego, k, flag);
    k_gather<<<2048, 256, 0, stream>>>(ego, users, items, d_out, k + 1, 1, flag);
  }
}

// Round 3
// 2101.398 us; speedup vs baseline: 1.1715x; 1.1715x over previous
//
#include <hip/hip_runtime.h>
#include <hip/hip_bf16.h>

// NGCF forward on MI355X.
// CSR build from unsorted COO (hist+scan+scatter, packed int2{col,valbits}),
// then 3x fused layer kernel: per wave, SpMM row accumulate (side in reg) +
// dense GCN/bi branch via v_readlane broadcasts (no shfl/LDS chain) with W
// staged fp32 in LDS, leaky_relu, write to alternate ego buffer.
// Normalize+gather only the 8192 output rows to d_out.
// Float dtype (f32 vs bf16) detected at runtime from user_emb's bit pattern.

#define N_USER 100000
#define N_ITEM 50000
#define N_NODES 150000
#define NE 4800000
#define D 64
#define NB1 ((N_NODES + 255) / 256)   // 586 blocks for the scan
#define LAYER_BLOCKS 1024             // 4 blocks/CU (32KB LDS each), all resident
#define LAYER_WAVES (LAYER_BLOCKS * 4)
#define ROWS_PER_WAVE ((N_NODES + LAYER_WAVES - 1) / LAYER_WAVES)  // 37

typedef __hip_bfloat16 bf16;

__device__ __forceinline__ float bits2f(unsigned short u) {
  return __uint_as_float(((unsigned int)u) << 16);
}
__device__ __forceinline__ float loadF(const void* p, long i, int f32) {
  if (f32) return ((const float*)p)[i];
  return bits2f(((const unsigned short*)p)[i]);
}
__device__ __forceinline__ float rlane(float x, int j) {
  return __int_as_float(__builtin_amdgcn_readlane(__float_as_int(x), j));
}

__global__ void k_zero(int* __restrict__ p, int n) {
  int i = blockIdx.x * blockDim.x + threadIdx.x;
  if (i < n) p[i] = 0;
}

// flag <- 1 if the float buffers are float32, 0 if bf16.
__global__ void k_detect(const unsigned short* __restrict__ ue, int* __restrict__ flag) {
  int bad = 0;
  for (int t = threadIdx.x; t < 512; t += 256) {
    float f = fabsf(bits2f(ue[t]));
    if (!(f < 1e4f)) bad = 1;  // catches NaN/Inf too
  }
  if (bad) atomicOr(flag, 1);
}

// ego[N,64] fp32 <- concat(user_emb, item_emb), 4 elems/thread
__global__ void k_init_ego(const void* __restrict__ ue, const void* __restrict__ ie,
                           float* __restrict__ ego, const int* __restrict__ flag) {
  int f32 = *flag;
  int i4 = (blockIdx.x * blockDim.x + threadIdx.x) * 4;
  if (i4 >= N_NODES * D) return;
  const int UD = N_USER * D;
  float4 v;
  if (f32) {
    const float* src = (i4 < UD) ? ((const float*)ue + i4) : ((const float*)ie + (i4 - UD));
    v = *(const float4*)src;
  } else {
    const unsigned short* src =
        (i4 < UD) ? ((const unsigned short*)ue + i4) : ((const unsigned short*)ie + (i4 - UD));
    ushort4 u = *(const ushort4*)src;
    v = make_float4(bits2f(u.x), bits2f(u.y), bits2f(u.z), bits2f(u.w));
  }
  *(float4*)(ego + i4) = v;
}

__global__ void k_hist(const int* __restrict__ row, int* __restrict__ hist) {
  int e = blockIdx.x * blockDim.x + threadIdx.x;
  if (e < NE) atomicAdd(&hist[row[e]], 1);
}

__global__ void k_scan1(int* __restrict__ rp, int* __restrict__ bsum) {
  __shared__ int sh[256];
  int i = blockIdx.x * 256 + threadIdx.x;
  int v = (i < N_NODES) ? rp[i] : 0;
  sh[threadIdx.x] = v;
  __syncthreads();
  for (int off = 1; off < 256; off <<= 1) {
    int t = (threadIdx.x >= off) ? sh[threadIdx.x - off] : 0;
    __syncthreads();
    sh[threadIdx.x] += t;
    __syncthreads();
  }
  if (i < N_NODES) rp[i] = sh[threadIdx.x] - v;
  if (threadIdx.x == 255) bsum[blockIdx.x] = sh[255];
}

__global__ void k_scan2(int* __restrict__ bsum) {
  __shared__ int sh[1024];
  int tid = threadIdx.x;
  int v = (tid < NB1) ? bsum[tid] : 0;
  sh[tid] = v;
  __syncthreads();
  for (int off = 1; off < 1024; off <<= 1) {
    int t = (tid >= off) ? sh[tid - off] : 0;
    __syncthreads();
    sh[tid] += t;
    __syncthreads();
  }
  if (tid < NB1) bsum[tid] = sh[tid] - v;
}

__global__ void k_scan3(int* __restrict__ rp, const int* __restrict__ bsum,
                        int* __restrict__ cursor) {
  int i = blockIdx.x * blockDim.x + threadIdx.x;
  if (i < N_NODES) {
    int v = rp[i] + bsum[i >> 8];
    rp[i] = v;
    cursor[i] = v;
  }
  if (i == 0) rp[N_NODES] = NE;
}

__global__ void k_scatter(const int* __restrict__ row, const int* __restrict__ col,
                          const void* __restrict__ val, int* __restrict__ cursor,
                          int2* __restrict__ csr, const int* __restrict__ flag) {
  int f32 = *flag;
  int e = blockIdx.x * blockDim.x + threadIdx.x;
  if (e < NE) {
    int r = row[e];
    int pos = atomicAdd(&cursor[r], 1);
    float v = loadF(val, e, f32);
    csr[pos] = make_int2(col[e], __float_as_int(v));
  }
}

// Fused layer: per wave, for each assigned row r:
//   side = sum_e val*ego_in[col]   (reg accumulate, lane = dim)
//   o    = bgc+bbi + side@Wgc + (ego_in[r]*side)@Wbi  via readlane broadcast
//   ego_out[r] = leaky_relu(o)
__global__ void __launch_bounds__(256) k_layer(
    const int* __restrict__ rp, const int2* __restrict__ csr,
    const float* __restrict__ ego_in, float* __restrict__ ego_out,
    const void* __restrict__ Wgc, const void* __restrict__ bgc,
    const void* __restrict__ Wbi, const void* __restrict__ bbi,
    int layer, const int* __restrict__ flag) {
  __shared__ float sWg[64 * 64];
  __shared__ float sWb[64 * 64];
  __shared__ float sbias[64];
  int f32 = *flag;
  int tid = threadIdx.x;
  for (int t = tid; t < 4096; t += 256) {
    sWg[t] = loadF(Wgc, (long)layer * 4096 + t, f32);
    sWb[t] = loadF(Wbi, (long)layer * 4096 + t, f32);
  }
  if (tid < 64)
    sbias[tid] = loadF(bgc, layer * 64 + tid, f32) + loadF(bbi, layer * 64 + tid, f32);
  __syncthreads();

  int lane = tid & 63;
  int wid = blockIdx.x * 4 + (tid >> 6);
  int r0 = wid * ROWS_PER_WAVE;
  int r1 = min(r0 + ROWS_PER_WAVE, N_NODES);

  for (int r = r0; r < r1; ++r) {
    int s = rp[r], e = rp[r + 1];
    float acc = 0.f;
    int i = s;
    for (; i + 4 <= e; i += 4) {
      int2 c0 = csr[i];
      int2 c1 = csr[i + 1];
      int2 c2 = csr[i + 2];
      int2 c3 = csr[i + 3];
      float g0 = ego_in[c0.x * D + lane];
      float g1 = ego_in[c1.x * D + lane];
      float g2 = ego_in[c2.x * D + lane];
      float g3 = ego_in[c3.x * D + lane];
      acc += __int_as_float(c0.y) * g0;
      acc += __int_as_float(c1.y) * g1;
      acc += __int_as_float(c2.y) * g2;
      acc += __int_as_float(c3.y) * g3;
    }
    for (; i < e; ++i) {
      int2 c = csr[i];
      acc += __int_as_float(c.y) * ego_in[c.x * D + lane];
    }
    float p = ego_in[r * D + lane] * acc;
    float o = sbias[lane];
#pragma unroll
    for (int j = 0; j < 64; ++j) {
      float sj = rlane(acc, j);
      float pj = rlane(p, j);
      o += sj * sWg[j * 64 + lane];
      o += pj * sWb[j * 64 + lane];
    }
    o = fmaxf(o, 0.2f * o);  // leaky_relu(0.2)
    ego_out[r * D + lane] = o;
  }
}

// gather 8192 output rows into out slice; optional l2-normalize per row.
__global__ void k_gather(const float* __restrict__ ego, const int* __restrict__ users,
                         const int* __restrict__ items, void* __restrict__ out,
                         int slice, int do_norm, const int* __restrict__ flag) {
  int f32 = *flag;
  int b = blockIdx.x * 4 + (threadIdx.x >> 6);
  int lane = threadIdx.x & 63;
  if (b >= 8192) return;
  int r = (b < 4096) ? users[b] : (N_USER + items[b - 4096]);
  float x = ego[r * D + lane];
  float scale = 1.f;
  if (do_norm) {
    float ss = x * x;
    for (int off = 32; off > 0; off >>= 1) ss += __shfl_xor(ss, off);
    scale = 1.f / fmaxf(sqrtf(ss), 1e-12f);
  }
  float y = x * scale;
  long idx = (long)b * 256 + slice * 64 + lane;
  if (f32) ((float*)out)[idx] = y;
  else ((bf16*)out)[idx] = __float2bfloat16(y);
}

extern "C" void kernel_launch(void* const* d_in, const int* in_sizes, int n_in,
                              void* d_out, int out_size, void* d_ws, size_t ws_size,
                              hipStream_t stream) {
  const void* ue = d_in[0];
  const void* ie = d_in[1];
  const void* Wgc = d_in[2];
  const void* bgc = d_in[3];
  const void* Wbi = d_in[4];
  const void* bbi = d_in[5];
  const void* aval = d_in[6];
  const int* arow = (const int*)d_in[7];
  const int* acol = (const int*)d_in[8];
  const int* users = (const int*)d_in[9];
  const int* items = (const int*)d_in[10];

  char* ws = (char*)d_ws;
  size_t off = 0;
  float* ego_a = (float*)(ws + off);  off += (size_t)N_NODES * D * 4;   // 38.4 MB
  float* ego_b = (float*)(ws + off);  off += (size_t)N_NODES * D * 4;   // 38.4 MB
  int2* csr = (int2*)(ws + off);      off += (size_t)NE * 8;            // 38.4 MB
  int* rp = (int*)(ws + off);         off += (size_t)(N_NODES + 64) * 4;
  int* cursor = (int*)(ws + off);     off += (size_t)N_NODES * 4;
  int* bsum = (int*)(ws + off);       off += 4096;
  int* flag = (int*)(ws + off);       off += 256;
  (void)ws_size;

  k_zero<<<1, 64, 0, stream>>>(flag, 1);
  k_detect<<<1, 256, 0, stream>>>((const unsigned short*)ue, flag);

  // CSR build (ws re-poisoned every call -> rebuild)
  k_zero<<<(N_NODES + 255) / 256, 256, 0, stream>>>(rp, N_NODES);
  k_init_ego<<<(N_NODES * D / 4 + 255) / 256, 256, 0, stream>>>(ue, ie, ego_a, flag);
  // slice 0 = raw (un-normalized) initial ego
  k_gather<<<2048, 256, 0, stream>>>(ego_a, users, items, d_out, 0, 0, flag);
  k_hist<<<(NE + 255) / 256, 256, 0, stream>>>(arow, rp);
  k_scan1<<<NB1, 256, 0, stream>>>(rp, bsum);
  k_scan2<<<1, 1024, 0, stream>>>(bsum);
  k_scan3<<<NB1, 256, 0, stream>>>(rp, bsum, cursor);
  k_scatter<<<(NE + 255) / 256, 256, 0, stream>>>(arow, acol, aval, cursor, csr, flag);

  float* bufs[4] = {ego_a, ego_b, ego_a, ego_b};
  for (int k = 0; k < 3; ++k) {
    k_layer<<<LAYER_BLOCKS, 256, 0, stream>>>(rp, csr, bufs[k], bufs[k + 1],
                                              Wgc, bgc, Wbi, bbi, k, flag);
    k_gather<<<2048, 256, 0, stream>>>(bufs[k + 1], users, items, d_out, k + 1, 1, flag);
  }
}

// Round 4
// 929.154 us; speedup vs baseline: 2.6495x; 2.2616x over previous
//
#include <hip/hip_runtime.h>
#include <hip/hip_bf16.h>

// NGCF forward on MI355X.
// CSR build from unsorted COO (hist+scan+scatter, packed int2{col,valbits}).
// Per layer:
//   k_spmm4: 4 rows/wave (16 lanes x float4 = row), unroll-8 edge loop,
//            gathers bf16 ego mirror (halved bytes), writes [side|prod] bf16.
//   k_dense: [N,128]@[128,64] GEMM via mfma_f32_16x16x32_bf16, B-frags in
//            VGPRs, W frag-ordered in LDS; epilogue bias+leaky -> ego32+egobf.
//   k_gather: normalize+gather the 8192 output rows to d_out.
// Float dtype (f32 vs bf16) detected at runtime from user_emb's bit pattern.

#define N_USER 100000
#define N_ITEM 50000
#define N_NODES 150000
#define NE 4800000
#define D 64
#define NB1 ((N_NODES + 255) / 256)  // 586 blocks for the scan
#define DG_BLOCKS 1024               // dense grid
#define NG (N_NODES / 16)            // 9375 row-groups of 16

typedef __hip_bfloat16 bf16;
typedef unsigned short u16;
typedef __attribute__((ext_vector_type(8))) short short8;
typedef __attribute__((ext_vector_type(4))) float float4v;

__device__ __forceinline__ float bits2f(u16 u) {
  return __uint_as_float(((unsigned int)u) << 16);
}
__device__ __forceinline__ u16 f2bits(float x) {
  union { bf16 h; u16 u; } c;
  c.h = __float2bfloat16(x);
  return c.u;
}
__device__ __forceinline__ float loadF(const void* p, long i, int f32) {
  if (f32) return ((const float*)p)[i];
  return bits2f(((const u16*)p)[i]);
}

__global__ void k_zero(int* __restrict__ p, int n) {
  int i = blockIdx.x * blockDim.x + threadIdx.x;
  if (i < n) p[i] = 0;
}

// flag <- 1 if the float buffers are float32, 0 if bf16.
__global__ void k_detect(const u16* __restrict__ ue, int* __restrict__ flag) {
  int bad = 0;
  for (int t = threadIdx.x; t < 512; t += 256) {
    float f = fabsf(bits2f(ue[t]));
    if (!(f < 1e4f)) bad = 1;  // catches NaN/Inf too
  }
  if (bad) atomicOr(flag, 1);
}

// ego32[N,64] fp32 and egobf[N,64] bf16 <- concat(user_emb, item_emb)
__global__ void k_init(const void* __restrict__ ue, const void* __restrict__ ie,
                       float* __restrict__ ego32, u16* __restrict__ egobf,
                       const int* __restrict__ flag) {
  int f32 = *flag;
  int i4 = (blockIdx.x * blockDim.x + threadIdx.x) * 4;
  if (i4 >= N_NODES * D) return;
  const int UD = N_USER * D;
  float4 v;
  ushort4 b;
  if (f32) {
    const float* s = (i4 < UD) ? ((const float*)ue + i4) : ((const float*)ie + (i4 - UD));
    v = *(const float4*)s;
    b = make_ushort4(f2bits(v.x), f2bits(v.y), f2bits(v.z), f2bits(v.w));
  } else {
    const u16* s = (i4 < UD) ? ((const u16*)ue + i4) : ((const u16*)ie + (i4 - UD));
    b = *(const ushort4*)s;
    v = make_float4(bits2f(b.x), bits2f(b.y), bits2f(b.z), bits2f(b.w));
  }
  *(float4*)(ego32 + i4) = v;
  *(ushort4*)(egobf + i4) = b;
}

__global__ void k_hist(const int* __restrict__ row, int* __restrict__ hist) {
  int e = blockIdx.x * blockDim.x + threadIdx.x;
  if (e < NE) atomicAdd(&hist[row[e]], 1);
}

__global__ void k_scan1(int* __restrict__ rp, int* __restrict__ bsum) {
  __shared__ int sh[256];
  int i = blockIdx.x * 256 + threadIdx.x;
  int v = (i < N_NODES) ? rp[i] : 0;
  sh[threadIdx.x] = v;
  __syncthreads();
  for (int off = 1; off < 256; off <<= 1) {
    int t = (threadIdx.x >= off) ? sh[threadIdx.x - off] : 0;
    __syncthreads();
    sh[threadIdx.x] += t;
    __syncthreads();
  }
  if (i < N_NODES) rp[i] = sh[threadIdx.x] - v;
  if (threadIdx.x == 255) bsum[blockIdx.x] = sh[255];
}

__global__ void k_scan2(int* __restrict__ bsum) {
  __shared__ int sh[1024];
  int tid = threadIdx.x;
  int v = (tid < NB1) ? bsum[tid] : 0;
  sh[tid] = v;
  __syncthreads();
  for (int off = 1; off < 1024; off <<= 1) {
    int t = (tid >= off) ? sh[tid - off] : 0;
    __syncthreads();
    sh[tid] += t;
    __syncthreads();
  }
  if (tid < NB1) bsum[tid] = sh[tid] - v;
}

__global__ void k_scan3(int* __restrict__ rp, const int* __restrict__ bsum,
                        int* __restrict__ cursor) {
  int i = blockIdx.x * blockDim.x + threadIdx.x;
  if (i < N_NODES) {
    int v = rp[i] + bsum[i >> 8];
    rp[i] = v;
    cursor[i] = v;
  }
  if (i == 0) rp[N_NODES] = NE;
}

__global__ void k_scatter(const int* __restrict__ row, const int* __restrict__ col,
                          const void* __restrict__ val, int* __restrict__ cursor,
                          int2* __restrict__ csr, const int* __restrict__ flag) {
  int f32 = *flag;
  int e = blockIdx.x * blockDim.x + threadIdx.x;
  if (e < NE) {
    int r = row[e];
    int pos = atomicAdd(&cursor[r], 1);
    float v = loadF(val, e, f32);
    csr[pos] = make_int2(col[e], __float_as_int(v));
  }
}

// 4 rows per wave (quarter-wave q = 16 lanes x float4 = one row).
// side = sum val*egobf[col]; prod = ego32[r]*side; write bf16 [side|prod].
__global__ void __launch_bounds__(256) k_spmm4(
    const int* __restrict__ rp, const int2* __restrict__ csr,
    const u16* __restrict__ egobf, const float* __restrict__ ego32,
    u16* __restrict__ spbf) {
  int tid = threadIdx.x;
  int wid = (blockIdx.x * 256 + tid) >> 6;
  int q = (tid >> 4) & 3;
  int ln = tid & 15;
  int r = wid * 4 + q;
  bool act = r < N_NODES;
  int rr = act ? r : 0;
  int s = rp[rr];
  int e = act ? rp[rr + 1] : s;

  float4 acc = make_float4(0.f, 0.f, 0.f, 0.f);
  int i = s;
  for (; i + 8 <= e; i += 8) {
    int2 cc[8];
#pragma unroll
    for (int t = 0; t < 8; ++t) cc[t] = csr[i + t];
    ushort4 gg[8];
#pragma unroll
    for (int t = 0; t < 8; ++t)
      gg[t] = *(const ushort4*)(egobf + (size_t)cc[t].x * 64 + ln * 4);
#pragma unroll
    for (int t = 0; t < 8; ++t) {
      float v = __int_as_float(cc[t].y);
      acc.x += v * bits2f(gg[t].x);
      acc.y += v * bits2f(gg[t].y);
      acc.z += v * bits2f(gg[t].z);
      acc.w += v * bits2f(gg[t].w);
    }
  }
  for (; i < e; ++i) {
    int2 c = csr[i];
    ushort4 g = *(const ushort4*)(egobf + (size_t)c.x * 64 + ln * 4);
    float v = __int_as_float(c.y);
    acc.x += v * bits2f(g.x);
    acc.y += v * bits2f(g.y);
    acc.z += v * bits2f(g.z);
    acc.w += v * bits2f(g.w);
  }
  if (act) {
    float4 er = *(const float4*)(ego32 + (size_t)r * 64 + ln * 4);
    u16* o = spbf + (size_t)r * 128 + ln * 4;
    *(ushort4*)o = make_ushort4(f2bits(acc.x), f2bits(acc.y), f2bits(acc.z), f2bits(acc.w));
    *(ushort4*)(o + 64) = make_ushort4(f2bits(er.x * acc.x), f2bits(er.y * acc.y),
                                       f2bits(er.z * acc.z), f2bits(er.w * acc.w));
  }
}

// ego_out = leaky_relu([side|prod] @ [Wg;Wb] + (bg+bb)) via MFMA 16x16x32 bf16.
// One wave = 16 rows x 64 cols; B-frags (4 col-tiles x 4 K-steps) in VGPRs.
// A-frag: A[m=lane&15][k=quad*8+j]; C/D: col=lane&15, row=quad*4+reg.
__global__ void __launch_bounds__(256) k_dense(
    const u16* __restrict__ spbf, const void* __restrict__ Wgc,
    const void* __restrict__ bgc, const void* __restrict__ Wbi,
    const void* __restrict__ bbi, float* __restrict__ ego32,
    u16* __restrict__ egobf, int layer, const int* __restrict__ flag) {
  __shared__ u16 sW[8192];   // frag-ordered [t][s2][lane][j]
  __shared__ float sbias[64];
  int f32 = *flag;
  int tid = threadIdx.x;
  for (int f = tid; f < 8192; f += 256) {
    int j = f & 7;
    int lane = (f >> 3) & 63;
    int s2 = (f >> 9) & 3;
    int t = f >> 11;
    int k = s2 * 32 + (lane >> 4) * 8 + j;
    int n = t * 16 + (lane & 15);
    float w = (k < 64) ? loadF(Wgc, (long)layer * 4096 + k * 64 + n, f32)
                       : loadF(Wbi, (long)layer * 4096 + (k - 64) * 64 + n, f32);
    sW[f] = f2bits(w);
  }
  if (tid < 64)
    sbias[tid] = loadF(bgc, layer * 64 + tid, f32) + loadF(bbi, layer * 64 + tid, f32);
  __syncthreads();

  int lane = tid & 63;
  int ln = lane & 15;
  int quad = lane >> 4;
  int gwave = blockIdx.x * 4 + (tid >> 6);

  short8 B[4][4];
#pragma unroll
  for (int t = 0; t < 4; ++t)
#pragma unroll
    for (int s2 = 0; s2 < 4; ++s2)
      B[t][s2] = *(const short8*)(sW + ((size_t)((t * 4 + s2) * 64 + lane)) * 8);

  float bt[4];
#pragma unroll
  for (int t = 0; t < 4; ++t) bt[t] = sbias[t * 16 + ln];

  for (int g = gwave; g < NG; g += DG_BLOCKS * 4) {
    int r0 = g * 16;
    float4v acc[4];
#pragma unroll
    for (int t = 0; t < 4; ++t) acc[t] = (float4v){0.f, 0.f, 0.f, 0.f};
#pragma unroll
    for (int s2 = 0; s2 < 4; ++s2) {
      short8 A = *(const short8*)(spbf + (size_t)(r0 + ln) * 128 + s2 * 32 + quad * 8);
#pragma unroll
      for (int t = 0; t < 4; ++t)
        acc[t] = __builtin_amdgcn_mfma_f32_16x16x32_bf16(A, B[t][s2], acc[t], 0, 0, 0);
    }
#pragma unroll
    for (int t = 0; t < 4; ++t) {
#pragma unroll
      for (int g2 = 0; g2 < 4; ++g2) {
        float x = acc[t][g2] + bt[t];
        x = fmaxf(x, 0.2f * x);  // leaky_relu(0.2)
        size_t idx = (size_t)(r0 + quad * 4 + g2) * 64 + t * 16 + ln;
        ego32[idx] = x;
        egobf[idx] = f2bits(x);
      }
    }
  }
}

// gather 8192 output rows into out slice; optional l2-normalize per row.
__global__ void k_gather(const float* __restrict__ ego, const int* __restrict__ users,
                         const int* __restrict__ items, void* __restrict__ out,
                         int slice, int do_norm, const int* __restrict__ flag) {
  int f32 = *flag;
  int b = blockIdx.x * 4 + (threadIdx.x >> 6);
  int lane = threadIdx.x & 63;
  if (b >= 8192) return;
  int r = (b < 4096) ? users[b] : (N_USER + items[b - 4096]);
  float x = ego[(size_t)r * D + lane];
  float scale = 1.f;
  if (do_norm) {
    float ss = x * x;
    for (int off = 32; off > 0; off >>= 1) ss += __shfl_xor(ss, off);
    scale = 1.f / fmaxf(sqrtf(ss), 1e-12f);
  }
  float y = x * scale;
  long idx = (long)b * 256 + slice * 64 + lane;
  if (f32) ((float*)out)[idx] = y;
  else ((bf16*)out)[idx] = __float2bfloat16(y);
}

extern "C" void kernel_launch(void* const* d_in, const int* in_sizes, int n_in,
                              void* d_out, int out_size, void* d_ws, size_t ws_size,
                              hipStream_t stream) {
  const void* ue = d_in[0];
  const void* ie = d_in[1];
  const void* Wgc = d_in[2];
  const void* bgc = d_in[3];
  const void* Wbi = d_in[4];
  const void* bbi = d_in[5];
  const void* aval = d_in[6];
  const int* arow = (const int*)d_in[7];
  const int* acol = (const int*)d_in[8];
  const int* users = (const int*)d_in[9];
  const int* items = (const int*)d_in[10];

  char* ws = (char*)d_ws;
  size_t off = 0;
  float* ego32 = (float*)(ws + off);  off += (size_t)N_NODES * D * 4;    // 38.4 MB
  u16* egobf = (u16*)(ws + off);      off += (size_t)N_NODES * D * 2;    // 19.2 MB
  u16* spbf = (u16*)(ws + off);       off += (size_t)N_NODES * 128 * 2;  // 38.4 MB
  int2* csr = (int2*)(ws + off);      off += (size_t)NE * 8;             // 38.4 MB
  int* rp = (int*)(ws + off);         off += (size_t)(N_NODES + 64) * 4;
  int* cursor = (int*)(ws + off);     off += (size_t)N_NODES * 4;
  int* bsum = (int*)(ws + off);       off += 4096;
  int* flag = (int*)(ws + off);       off += 256;
  (void)ws_size;

  k_zero<<<1, 64, 0, stream>>>(flag, 1);
  k_detect<<<1, 256, 0, stream>>>((const u16*)ue, flag);

  // CSR build (ws re-poisoned every call -> rebuild)
  k_zero<<<(N_NODES + 255) / 256, 256, 0, stream>>>(rp, N_NODES);
  k_init<<<(N_NODES * D / 4 + 255) / 256, 256, 0, stream>>>(ue, ie, ego32, egobf, flag);
  // slice 0 = raw (un-normalized) initial ego
  k_gather<<<2048, 256, 0, stream>>>(ego32, users, items, d_out, 0, 0, flag);
  k_hist<<<(NE + 255) / 256, 256, 0, stream>>>(arow, rp);
  k_scan1<<<NB1, 256, 0, stream>>>(rp, bsum);
  k_scan2<<<1, 1024, 0, stream>>>(bsum);
  k_scan3<<<NB1, 256, 0, stream>>>(rp, bsum, cursor);
  k_scatter<<<(NE + 255) / 256, 256, 0, stream>>>(arow, acol, aval, cursor, csr, flag);

  for (int k = 0; k < 3; ++k) {
    k_spmm4<<<(N_NODES / 4 + 3) / 4 + 1, 256, 0, stream>>>(rp, csr, egobf, ego32, spbf);
    k_dense<<<DG_BLOCKS, 256, 0, stream>>>(spbf, Wgc, bgc, Wbi, bbi, ego32, egobf, k, flag);
    k_gather<<<2048, 256, 0, stream>>>(ego32, users, items, d_out, k + 1, 1, flag);
  }
}